// Round 1
// baseline (758.686 us; speedup 1.0000x reference)
//
#include <hip/hip_runtime.h>

#define N_NODES 100000
#define N_EDGES 1200000
#define DIM 64
#define N_GRAPHS 128
#define N_LAYERS 5

// ---------------- CSR build ----------------

__global__ __launch_bounds__(256) void hist_kernel(const int* __restrict__ dst, int* __restrict__ cnt) {
  int i = blockIdx.x * 256 + threadIdx.x;
  if (i < N_EDGES) atomicAdd(&cnt[dst[i]], 1);
}

__global__ __launch_bounds__(1024) void scan1_kernel(const int* __restrict__ cnt,
                                                     int* __restrict__ incl,
                                                     int* __restrict__ partials) {
  __shared__ int sm[1024];
  int t = threadIdx.x;
  int i = blockIdx.x * 1024 + t;
  int v = (i < N_NODES) ? cnt[i] : 0;
  sm[t] = v;
  __syncthreads();
  for (int off = 1; off < 1024; off <<= 1) {
    int x = (t >= off) ? sm[t - off] : 0;
    __syncthreads();
    sm[t] += x;
    __syncthreads();
  }
  if (i < N_NODES) incl[i] = sm[t];
  if (t == 1023) partials[blockIdx.x] = sm[1023];
}

__global__ __launch_bounds__(1024) void scan2_kernel(int* __restrict__ partials, int nb) {
  __shared__ int sm[1024];
  int t = threadIdx.x;
  int v = (t < nb) ? partials[t] : 0;
  sm[t] = v;
  __syncthreads();
  for (int off = 1; off < 1024; off <<= 1) {
    int x = (t >= off) ? sm[t - off] : 0;
    __syncthreads();
    sm[t] += x;
    __syncthreads();
  }
  if (t < nb) partials[t] = sm[t];
}

__global__ __launch_bounds__(1024) void finalize_kernel(const int* __restrict__ incl,
                                                        const int* __restrict__ partials,
                                                        const int* __restrict__ cnt,
                                                        int* __restrict__ rowptr,
                                                        int* __restrict__ cursor) {
  int i = blockIdx.x * 1024 + threadIdx.x;
  if (i < N_NODES) {
    int add = blockIdx.x ? partials[blockIdx.x - 1] : 0;
    int v = incl[i] + add;         // inclusive prefix
    rowptr[i + 1] = v;
    cursor[i] = v - cnt[i];        // exclusive prefix = segment start
    if (i == 0) rowptr[0] = 0;
  }
}

__global__ __launch_bounds__(256) void scatter_kernel(const int* __restrict__ src,
                                                      const int* __restrict__ dst,
                                                      int* __restrict__ cursor,
                                                      int* __restrict__ ssrc) {
  int i = blockIdx.x * 256 + threadIdx.x;
  if (i < N_EDGES) {
    int p = atomicAdd(&cursor[dst[i]], 1);
    ssrc[p] = src[i];
  }
}

// ---------------- per-layer aggregation: z = h + sum_{j in N(i)} h_j ----------------
// one 64-lane wave per node, lane d owns dim d; 4 nodes per 256-thread block.

__global__ __launch_bounds__(256) void agg_kernel(const float* __restrict__ h,
                                                  const int* __restrict__ rowptr,
                                                  const int* __restrict__ ssrc,
                                                  float* __restrict__ z) {
  int node = blockIdx.x * 4 + (threadIdx.x >> 6);
  int d = threadIdx.x & 63;
  if (node >= N_NODES) return;
  float acc = h[node * DIM + d];
  int s = rowptr[node], e = rowptr[node + 1];
  #pragma unroll 2
  for (int j = s; j < e; ++j) {
    int u = ssrc[j];                  // wave-uniform load
    acc += h[u * DIM + d];            // coalesced 256B row
  }
  z[node * DIM + d] = acc;
}

// ---------------- fused MLP: out = relu((relu((z@W1+b1)*s+t))@W2+b2) ----------------
// tile = 128 nodes, 128 threads, each thread -> 8 nodes x 8 dims.
// zs: row-major [128][68] (stride 68 -> 16B aligned, broadcast-friendly reads).

#define ZSTRIDE 68

__global__ __launch_bounds__(128) void mlp_kernel(const float* __restrict__ z,
                                                  float* __restrict__ hout,
                                                  const float* __restrict__ W1,
                                                  const float* __restrict__ b1,
                                                  const float* __restrict__ gam,
                                                  const float* __restrict__ bet,
                                                  const float* __restrict__ W2,
                                                  const float* __restrict__ b2) {
  __shared__ float zs[128 * ZSTRIDE];
  __shared__ float wls[64 * 64];
  const int t = threadIdx.x;
  const int base = blockIdx.x * 128;

  // stage z tile (coalesced global float4 reads)
  #pragma unroll
  for (int i = 0; i < 16; ++i) {
    int f = i * 128 + t;            // float4 slot over 2048
    int n = f >> 4;
    int d = (f & 15) << 2;
    int gn = base + n;
    if (gn >= N_NODES) gn = N_NODES - 1;   // clamp; garbage rows never stored
    *(float4*)(zs + n * ZSTRIDE + d) = *(const float4*)(z + gn * DIM + d);
  }
  // stage W1
  #pragma unroll
  for (int i = 0; i < 8; ++i) {
    int f = (i * 128 + t) * 4;
    *(float4*)(wls + f) = *(const float4*)(W1 + f);
  }
  __syncthreads();

  const int m = t & 7;              // dim group
  const int gq = t >> 3;            // node group 0..15
  const int c0 = m * 8;

  float acc[8][8];
  #pragma unroll
  for (int j = 0; j < 8; ++j)
    #pragma unroll
    for (int i = 0; i < 8; ++i) acc[j][i] = 0.f;

  #pragma unroll 2
  for (int k0 = 0; k0 < 64; k0 += 4) {
    float zv[8][4];
    #pragma unroll
    for (int j = 0; j < 8; ++j)
      *(float4*)zv[j] = *(const float4*)(zs + (gq + 16 * j) * ZSTRIDE + k0);
    #pragma unroll
    for (int kk = 0; kk < 4; ++kk) {
      float wa[8];
      *(float4*)&wa[0] = *(const float4*)(wls + (k0 + kk) * 64 + c0);
      *(float4*)&wa[4] = *(const float4*)(wls + (k0 + kk) * 64 + c0 + 4);
      #pragma unroll
      for (int j = 0; j < 8; ++j) {
        float zz = zv[j][kk];
        #pragma unroll
        for (int i = 0; i < 8; ++i) acc[j][i] = fmaf(zz, wa[i], acc[j][i]);
      }
    }
  }

  // BN fold (eval: mean=0, var=1) + bias + relu
  const float BNR = 0.99999500003749971893f;   // 1/sqrt(1+1e-5)
  float s_[8], o_[8];
  #pragma unroll
  for (int i = 0; i < 8; ++i) {
    float sc = gam[c0 + i] * BNR;
    s_[i] = sc;
    o_[i] = fmaf(b1[c0 + i], sc, bet[c0 + i]);
  }
  #pragma unroll
  for (int j = 0; j < 8; ++j)
    #pragma unroll
    for (int i = 0; i < 8; ++i) {
      float v = fmaf(acc[j][i], s_[i], o_[i]);
      acc[j][i] = v > 0.f ? v : 0.f;
    }

  __syncthreads();   // all matmul1 LDS reads done

  // write z1 back to zs; stage W2
  #pragma unroll
  for (int j = 0; j < 8; ++j) {
    int n = gq + 16 * j;
    float4 a = make_float4(acc[j][0], acc[j][1], acc[j][2], acc[j][3]);
    float4 b = make_float4(acc[j][4], acc[j][5], acc[j][6], acc[j][7]);
    *(float4*)(zs + n * ZSTRIDE + c0) = a;
    *(float4*)(zs + n * ZSTRIDE + c0 + 4) = b;
  }
  #pragma unroll
  for (int i = 0; i < 8; ++i) {
    int f = (i * 128 + t) * 4;
    *(float4*)(wls + f) = *(const float4*)(W2 + f);
  }
  __syncthreads();

  float acc2[8][8];
  #pragma unroll
  for (int j = 0; j < 8; ++j)
    #pragma unroll
    for (int i = 0; i < 8; ++i) acc2[j][i] = 0.f;

  #pragma unroll 2
  for (int k0 = 0; k0 < 64; k0 += 4) {
    float zv[8][4];
    #pragma unroll
    for (int j = 0; j < 8; ++j)
      *(float4*)zv[j] = *(const float4*)(zs + (gq + 16 * j) * ZSTRIDE + k0);
    #pragma unroll
    for (int kk = 0; kk < 4; ++kk) {
      float wa[8];
      *(float4*)&wa[0] = *(const float4*)(wls + (k0 + kk) * 64 + c0);
      *(float4*)&wa[4] = *(const float4*)(wls + (k0 + kk) * 64 + c0 + 4);
      #pragma unroll
      for (int j = 0; j < 8; ++j) {
        float zz = zv[j][kk];
        #pragma unroll
        for (int i = 0; i < 8; ++i) acc2[j][i] = fmaf(zz, wa[i], acc2[j][i]);
      }
    }
  }

  float bb[8];
  #pragma unroll
  for (int i = 0; i < 8; ++i) bb[i] = b2[c0 + i];
  #pragma unroll
  for (int j = 0; j < 8; ++j) {
    int gn = base + gq + 16 * j;
    if (gn < N_NODES) {
      float4 a, b;
      a.x = fmaxf(acc2[j][0] + bb[0], 0.f);
      a.y = fmaxf(acc2[j][1] + bb[1], 0.f);
      a.z = fmaxf(acc2[j][2] + bb[2], 0.f);
      a.w = fmaxf(acc2[j][3] + bb[3], 0.f);
      b.x = fmaxf(acc2[j][4] + bb[4], 0.f);
      b.y = fmaxf(acc2[j][5] + bb[5], 0.f);
      b.z = fmaxf(acc2[j][6] + bb[6], 0.f);
      b.w = fmaxf(acc2[j][7] + bb[7], 0.f);
      *(float4*)(hout + gn * DIM + c0) = a;
      *(float4*)(hout + gn * DIM + c0 + 4) = b;
    }
  }
}

// ---------------- pool (batch is sorted) + head ----------------

__global__ __launch_bounds__(256) void pool_head_kernel(const float* __restrict__ h,
                                                        const int* __restrict__ batch,
                                                        const float* __restrict__ lw,
                                                        const float* __restrict__ lb,
                                                        float* __restrict__ out) {
  __shared__ float red[4][64];
  int g = blockIdx.x;
  int t = threadIdx.x, w = t >> 6, d = t & 63;
  // lower_bound(g) and lower_bound(g+1) on sorted batch
  int lo = 0, hi = N_NODES;
  while (lo < hi) { int mid = (lo + hi) >> 1; if (batch[mid] < g) lo = mid + 1; else hi = mid; }
  int start = lo;
  hi = N_NODES;
  while (lo < hi) { int mid = (lo + hi) >> 1; if (batch[mid] < g + 1) lo = mid + 1; else hi = mid; }
  int end = lo;

  float acc = 0.f;
  for (int i = start + w; i < end; i += 4) acc += h[i * DIM + d];
  red[w][d] = acc;
  __syncthreads();
  if (w == 0) {
    float prow = red[0][d] + red[1][d] + red[2][d] + red[3][d];
    red[0][d] = prow;
  }
  __syncthreads();
  if (w == 0) {
    float o = lb[d];
    #pragma unroll
    for (int k = 0; k < 64; ++k) o += red[0][k] * lw[k * 64 + d];
    out[g * 64 + d] = fmaxf(o, 0.f);
  }
}

// ---------------- host ----------------

extern "C" void kernel_launch(void* const* d_in, const int* in_sizes, int n_in,
                              void* d_out, int out_size, void* d_ws, size_t ws_size,
                              hipStream_t stream) {
  const float* x      = (const float*)d_in[0];
  const int*   ei     = (const int*)d_in[1];
  const int*   srcp   = ei;
  const int*   dstp   = ei + N_EDGES;
  const int*   batch  = (const int*)d_in[2];
  const float* W1s    = (const float*)d_in[3];
  const float* b1s    = (const float*)d_in[4];
  const float* gammas = (const float*)d_in[5];
  const float* betas  = (const float*)d_in[6];
  const float* W2s    = (const float*)d_in[7];
  const float* b2s    = (const float*)d_in[8];
  const float* lin1_w = (const float*)d_in[9];
  const float* lin1_b = (const float*)d_in[10];

  char* ws = (char*)d_ws;
  const size_t HBYTES = (size_t)N_NODES * DIM * sizeof(float);   // 25.6 MB
  float* hA = (float*)ws;
  float* hB = (float*)(ws + HBYTES);
  int*   cnt      = (int*)(ws + 2 * HBYTES);
  const int PAD_N = 100352;                 // 98*1024
  int*   incl     = cnt + PAD_N;
  int*   rowptr   = incl + PAD_N;           // N_NODES+1 used
  int*   cursor   = rowptr + PAD_N;
  int*   partials = cursor + PAD_N;
  int*   ssrc     = partials + 1024;

  const int SCAN_BLOCKS = (N_NODES + 1023) / 1024;   // 98
  const int EDGE_BLOCKS = (N_EDGES + 255) / 256;     // 4688

  hipMemsetAsync(cnt, 0, (size_t)N_NODES * sizeof(int), stream);
  hist_kernel<<<EDGE_BLOCKS, 256, 0, stream>>>(dstp, cnt);
  scan1_kernel<<<SCAN_BLOCKS, 1024, 0, stream>>>(cnt, incl, partials);
  scan2_kernel<<<1, 1024, 0, stream>>>(partials, SCAN_BLOCKS);
  finalize_kernel<<<SCAN_BLOCKS, 1024, 0, stream>>>(incl, partials, cnt, rowptr, cursor);
  scatter_kernel<<<EDGE_BLOCKS, 256, 0, stream>>>(srcp, dstp, cursor, ssrc);

  const int AGG_BLOCKS = (N_NODES + 3) / 4;          // 25000
  const int MLP_BLOCKS = (N_NODES + 127) / 128;      // 782

  const float* hin = x;
  for (int l = 0; l < N_LAYERS; ++l) {
    agg_kernel<<<AGG_BLOCKS, 256, 0, stream>>>(hin, rowptr, ssrc, hB);
    mlp_kernel<<<MLP_BLOCKS, 128, 0, stream>>>(hB, hA,
        W1s + (size_t)l * DIM * DIM, b1s + (size_t)l * DIM,
        gammas + (size_t)l * DIM, betas + (size_t)l * DIM,
        W2s + (size_t)l * DIM * DIM, b2s + (size_t)l * DIM);
    hin = hA;
  }

  pool_head_kernel<<<N_GRAPHS, 256, 0, stream>>>(hA, batch, lin1_w, lin1_b, (float*)d_out);
}

// Round 2
// 662.653 us; speedup vs baseline: 1.1449x; 1.1449x over previous
//
#include <hip/hip_runtime.h>

#define N_NODES 100000
#define N_EDGES 1200000
#define DIM 64
#define N_GRAPHS 128
#define N_LAYERS 5

typedef unsigned short ushort_t;
typedef unsigned int uint_t;

__device__ __forceinline__ float bf2f(ushort_t s) {
  return __uint_as_float(((uint_t)s) << 16);
}
__device__ __forceinline__ ushort_t f2bf(float f) {
  uint_t u = __float_as_uint(f);
  uint_t r = u + 0x7fffu + ((u >> 16) & 1u);   // RNE
  return (ushort_t)(r >> 16);
}
__device__ __forceinline__ uint_t pack2(float a, float b) {
  return (uint_t)f2bf(a) | ((uint_t)f2bf(b) << 16);
}

// ---------------- fp32 -> bf16 convert (x only, once) ----------------

__global__ __launch_bounds__(256) void conv_kernel(const float* __restrict__ x,
                                                   ushort_t* __restrict__ xb) {
  int i = blockIdx.x * 256 + threadIdx.x;   // 8 elems per thread
  int base = i * 8;
  if (base >= N_NODES * DIM) return;
  float4 a = *(const float4*)(x + base);
  float4 b = *(const float4*)(x + base + 4);
  uint4 o;
  o.x = pack2(a.x, a.y);
  o.y = pack2(a.z, a.w);
  o.z = pack2(b.x, b.y);
  o.w = pack2(b.z, b.w);
  *(uint4*)(xb + base) = o;
}

// ---------------- CSR build ----------------

__global__ __launch_bounds__(256) void hist_kernel(const int* __restrict__ dst, int* __restrict__ cnt) {
  int i = blockIdx.x * 256 + threadIdx.x;
  if (i < N_EDGES) atomicAdd(&cnt[dst[i]], 1);
}

__global__ __launch_bounds__(1024) void scan1_kernel(const int* __restrict__ cnt,
                                                     int* __restrict__ incl,
                                                     int* __restrict__ partials) {
  __shared__ int sm[1024];
  int t = threadIdx.x;
  int i = blockIdx.x * 1024 + t;
  int v = (i < N_NODES) ? cnt[i] : 0;
  sm[t] = v;
  __syncthreads();
  for (int off = 1; off < 1024; off <<= 1) {
    int x = (t >= off) ? sm[t - off] : 0;
    __syncthreads();
    sm[t] += x;
    __syncthreads();
  }
  if (i < N_NODES) incl[i] = sm[t];
  if (t == 1023) partials[blockIdx.x] = sm[1023];
}

__global__ __launch_bounds__(1024) void scan2_kernel(int* __restrict__ partials, int nb) {
  __shared__ int sm[1024];
  int t = threadIdx.x;
  int v = (t < nb) ? partials[t] : 0;
  sm[t] = v;
  __syncthreads();
  for (int off = 1; off < 1024; off <<= 1) {
    int x = (t >= off) ? sm[t - off] : 0;
    __syncthreads();
    sm[t] += x;
    __syncthreads();
  }
  if (t < nb) partials[t] = sm[t];
}

__global__ __launch_bounds__(1024) void finalize_kernel(const int* __restrict__ incl,
                                                        const int* __restrict__ partials,
                                                        const int* __restrict__ cnt,
                                                        int* __restrict__ rowptr,
                                                        int* __restrict__ cursor) {
  int i = blockIdx.x * 1024 + threadIdx.x;
  if (i < N_NODES) {
    int add = blockIdx.x ? partials[blockIdx.x - 1] : 0;
    int v = incl[i] + add;         // inclusive prefix
    rowptr[i + 1] = v;
    cursor[i] = v - cnt[i];        // exclusive prefix = segment start
    if (i == 0) rowptr[0] = 0;
  }
}

__global__ __launch_bounds__(256) void scatter_kernel(const int* __restrict__ src,
                                                      const int* __restrict__ dst,
                                                      int* __restrict__ cursor,
                                                      int* __restrict__ ssrc) {
  int i = blockIdx.x * 256 + threadIdx.x;
  if (i < N_EDGES) {
    int p = atomicAdd(&cursor[dst[i]], 1);
    ssrc[p] = src[i];
  }
}

// ---------------- per-layer aggregation: z = h + sum_{j in N(i)} h_j ----------------
// h is bf16 [N][64]; one 64-lane wave per node, lane d owns dim d; z fp32.

__global__ __launch_bounds__(256) void agg_kernel(const ushort_t* __restrict__ h,
                                                  const int* __restrict__ rowptr,
                                                  const int* __restrict__ ssrc,
                                                  float* __restrict__ z) {
  int node = blockIdx.x * 4 + (threadIdx.x >> 6);
  int d = threadIdx.x & 63;
  if (node >= N_NODES) return;
  float a0 = bf2f(h[node * DIM + d]);
  float a1 = 0.f, a2 = 0.f, a3 = 0.f;
  int s = rowptr[node], e = rowptr[node + 1];
  int j = s;
  for (; j + 4 <= e; j += 4) {
    int u0 = ssrc[j], u1 = ssrc[j + 1], u2 = ssrc[j + 2], u3 = ssrc[j + 3];
    ushort_t r0 = h[u0 * DIM + d];
    ushort_t r1 = h[u1 * DIM + d];
    ushort_t r2 = h[u2 * DIM + d];
    ushort_t r3 = h[u3 * DIM + d];
    a0 += bf2f(r0);
    a1 += bf2f(r1);
    a2 += bf2f(r2);
    a3 += bf2f(r3);
  }
  for (; j < e; ++j) a1 += bf2f(h[ssrc[j] * DIM + d]);
  z[node * DIM + d] = (a0 + a1) + (a2 + a3);
}

// ---------------- fused MLP: out = relu((relu((z@W1+b1)*s+t))@W2+b2) ----------------
// z fp32 in, hout bf16 out. tile = 128 nodes, 128 threads, thread -> 8n x 8d.

#define ZSTRIDE 68

__global__ __launch_bounds__(128) void mlp_kernel(const float* __restrict__ z,
                                                  ushort_t* __restrict__ hout,
                                                  const float* __restrict__ W1,
                                                  const float* __restrict__ b1,
                                                  const float* __restrict__ gam,
                                                  const float* __restrict__ bet,
                                                  const float* __restrict__ W2,
                                                  const float* __restrict__ b2) {
  __shared__ float zs[128 * ZSTRIDE];
  __shared__ float wls[64 * 64];
  const int t = threadIdx.x;
  const int base = blockIdx.x * 128;

  // stage z tile (coalesced global float4 reads)
  #pragma unroll
  for (int i = 0; i < 16; ++i) {
    int f = i * 128 + t;            // float4 slot over 2048
    int n = f >> 4;
    int d = (f & 15) << 2;
    int gn = base + n;
    if (gn >= N_NODES) gn = N_NODES - 1;   // clamp; garbage rows never stored
    *(float4*)(zs + n * ZSTRIDE + d) = *(const float4*)(z + gn * DIM + d);
  }
  // stage W1
  #pragma unroll
  for (int i = 0; i < 8; ++i) {
    int f = (i * 128 + t) * 4;
    *(float4*)(wls + f) = *(const float4*)(W1 + f);
  }
  __syncthreads();

  const int m = t & 7;              // dim group
  const int gq = t >> 3;            // node group 0..15
  const int c0 = m * 8;

  float acc[8][8];
  #pragma unroll
  for (int j = 0; j < 8; ++j)
    #pragma unroll
    for (int i = 0; i < 8; ++i) acc[j][i] = 0.f;

  #pragma unroll 2
  for (int k0 = 0; k0 < 64; k0 += 4) {
    float zv[8][4];
    #pragma unroll
    for (int j = 0; j < 8; ++j)
      *(float4*)zv[j] = *(const float4*)(zs + (gq + 16 * j) * ZSTRIDE + k0);
    #pragma unroll
    for (int kk = 0; kk < 4; ++kk) {
      float wa[8];
      *(float4*)&wa[0] = *(const float4*)(wls + (k0 + kk) * 64 + c0);
      *(float4*)&wa[4] = *(const float4*)(wls + (k0 + kk) * 64 + c0 + 4);
      #pragma unroll
      for (int j = 0; j < 8; ++j) {
        float zz = zv[j][kk];
        #pragma unroll
        for (int i = 0; i < 8; ++i) acc[j][i] = fmaf(zz, wa[i], acc[j][i]);
      }
    }
  }

  // BN fold (eval: mean=0, var=1) + bias + relu
  const float BNR = 0.99999500003749971893f;   // 1/sqrt(1+1e-5)
  float s_[8], o_[8];
  #pragma unroll
  for (int i = 0; i < 8; ++i) {
    float sc = gam[c0 + i] * BNR;
    s_[i] = sc;
    o_[i] = fmaf(b1[c0 + i], sc, bet[c0 + i]);
  }
  #pragma unroll
  for (int j = 0; j < 8; ++j)
    #pragma unroll
    for (int i = 0; i < 8; ++i) {
      float v = fmaf(acc[j][i], s_[i], o_[i]);
      acc[j][i] = v > 0.f ? v : 0.f;
    }

  __syncthreads();   // all matmul1 LDS reads done

  // write z1 back to zs; stage W2
  #pragma unroll
  for (int j = 0; j < 8; ++j) {
    int n = gq + 16 * j;
    float4 a = make_float4(acc[j][0], acc[j][1], acc[j][2], acc[j][3]);
    float4 b = make_float4(acc[j][4], acc[j][5], acc[j][6], acc[j][7]);
    *(float4*)(zs + n * ZSTRIDE + c0) = a;
    *(float4*)(zs + n * ZSTRIDE + c0 + 4) = b;
  }
  #pragma unroll
  for (int i = 0; i < 8; ++i) {
    int f = (i * 128 + t) * 4;
    *(float4*)(wls + f) = *(const float4*)(W2 + f);
  }
  __syncthreads();

  float acc2[8][8];
  #pragma unroll
  for (int j = 0; j < 8; ++j)
    #pragma unroll
    for (int i = 0; i < 8; ++i) acc2[j][i] = 0.f;

  #pragma unroll 2
  for (int k0 = 0; k0 < 64; k0 += 4) {
    float zv[8][4];
    #pragma unroll
    for (int j = 0; j < 8; ++j)
      *(float4*)zv[j] = *(const float4*)(zs + (gq + 16 * j) * ZSTRIDE + k0);
    #pragma unroll
    for (int kk = 0; kk < 4; ++kk) {
      float wa[8];
      *(float4*)&wa[0] = *(const float4*)(wls + (k0 + kk) * 64 + c0);
      *(float4*)&wa[4] = *(const float4*)(wls + (k0 + kk) * 64 + c0 + 4);
      #pragma unroll
      for (int j = 0; j < 8; ++j) {
        float zz = zv[j][kk];
        #pragma unroll
        for (int i = 0; i < 8; ++i) acc2[j][i] = fmaf(zz, wa[i], acc2[j][i]);
      }
    }
  }

  float bb[8];
  #pragma unroll
  for (int i = 0; i < 8; ++i) bb[i] = b2[c0 + i];
  #pragma unroll
  for (int j = 0; j < 8; ++j) {
    int gn = base + gq + 16 * j;
    if (gn < N_NODES) {
      uint4 o;
      float v0 = fmaxf(acc2[j][0] + bb[0], 0.f);
      float v1 = fmaxf(acc2[j][1] + bb[1], 0.f);
      float v2 = fmaxf(acc2[j][2] + bb[2], 0.f);
      float v3 = fmaxf(acc2[j][3] + bb[3], 0.f);
      float v4 = fmaxf(acc2[j][4] + bb[4], 0.f);
      float v5 = fmaxf(acc2[j][5] + bb[5], 0.f);
      float v6 = fmaxf(acc2[j][6] + bb[6], 0.f);
      float v7 = fmaxf(acc2[j][7] + bb[7], 0.f);
      o.x = pack2(v0, v1);
      o.y = pack2(v2, v3);
      o.z = pack2(v4, v5);
      o.w = pack2(v6, v7);
      *(uint4*)(hout + gn * DIM + c0) = o;
    }
  }
}

// ---------------- pool (batch is sorted) + head ----------------

__global__ __launch_bounds__(256) void pool_head_kernel(const ushort_t* __restrict__ h,
                                                        const int* __restrict__ batch,
                                                        const float* __restrict__ lw,
                                                        const float* __restrict__ lb,
                                                        float* __restrict__ out) {
  __shared__ float red[4][64];
  int g = blockIdx.x;
  int t = threadIdx.x, w = t >> 6, d = t & 63;
  // lower_bound(g) and lower_bound(g+1) on sorted batch
  int lo = 0, hi = N_NODES;
  while (lo < hi) { int mid = (lo + hi) >> 1; if (batch[mid] < g) lo = mid + 1; else hi = mid; }
  int start = lo;
  hi = N_NODES;
  while (lo < hi) { int mid = (lo + hi) >> 1; if (batch[mid] < g + 1) lo = mid + 1; else hi = mid; }
  int end = lo;

  float acc = 0.f;
  for (int i = start + w; i < end; i += 4) acc += bf2f(h[i * DIM + d]);
  red[w][d] = acc;
  __syncthreads();
  if (w == 0) {
    float prow = red[0][d] + red[1][d] + red[2][d] + red[3][d];
    red[0][d] = prow;
  }
  __syncthreads();
  if (w == 0) {
    float o = lb[d];
    #pragma unroll
    for (int k = 0; k < 64; ++k) o += red[0][k] * lw[k * 64 + d];
    out[g * 64 + d] = fmaxf(o, 0.f);
  }
}

// ---------------- host ----------------

extern "C" void kernel_launch(void* const* d_in, const int* in_sizes, int n_in,
                              void* d_out, int out_size, void* d_ws, size_t ws_size,
                              hipStream_t stream) {
  const float* x      = (const float*)d_in[0];
  const int*   ei     = (const int*)d_in[1];
  const int*   srcp   = ei;
  const int*   dstp   = ei + N_EDGES;
  const int*   batch  = (const int*)d_in[2];
  const float* W1s    = (const float*)d_in[3];
  const float* b1s    = (const float*)d_in[4];
  const float* gammas = (const float*)d_in[5];
  const float* betas  = (const float*)d_in[6];
  const float* W2s    = (const float*)d_in[7];
  const float* b2s    = (const float*)d_in[8];
  const float* lin1_w = (const float*)d_in[9];
  const float* lin1_b = (const float*)d_in[10];

  char* ws = (char*)d_ws;
  const size_t ZBYTES  = (size_t)N_NODES * DIM * sizeof(float);     // 25.6 MB
  const size_t HBBYTES = (size_t)N_NODES * DIM * sizeof(ushort_t);  // 12.8 MB
  float*    zbuf = (float*)ws;
  ushort_t* xb   = (ushort_t*)(ws + ZBYTES);
  ushort_t* h1   = (ushort_t*)(ws + ZBYTES + HBBYTES);
  int*      cnt  = (int*)(ws + ZBYTES + 2 * HBBYTES);
  const int PAD_N = 100352;                 // 98*1024
  int*   incl     = cnt + PAD_N;
  int*   rowptr   = incl + PAD_N;           // N_NODES+1 used
  int*   cursor   = rowptr + PAD_N;
  int*   partials = cursor + PAD_N;
  int*   ssrc     = partials + 1024;

  const int SCAN_BLOCKS = (N_NODES + 1023) / 1024;   // 98
  const int EDGE_BLOCKS = (N_EDGES + 255) / 256;     // 4688

  hipMemsetAsync(cnt, 0, (size_t)N_NODES * sizeof(int), stream);
  conv_kernel<<<(N_NODES * DIM / 8 + 255) / 256, 256, 0, stream>>>(x, xb);
  hist_kernel<<<EDGE_BLOCKS, 256, 0, stream>>>(dstp, cnt);
  scan1_kernel<<<SCAN_BLOCKS, 1024, 0, stream>>>(cnt, incl, partials);
  scan2_kernel<<<1, 1024, 0, stream>>>(partials, SCAN_BLOCKS);
  finalize_kernel<<<SCAN_BLOCKS, 1024, 0, stream>>>(incl, partials, cnt, rowptr, cursor);
  scatter_kernel<<<EDGE_BLOCKS, 256, 0, stream>>>(srcp, dstp, cursor, ssrc);

  const int AGG_BLOCKS = (N_NODES + 3) / 4;          // 25000
  const int MLP_BLOCKS = (N_NODES + 127) / 128;      // 782

  const ushort_t* hin = xb;
  for (int l = 0; l < N_LAYERS; ++l) {
    agg_kernel<<<AGG_BLOCKS, 256, 0, stream>>>(hin, rowptr, ssrc, zbuf);
    mlp_kernel<<<MLP_BLOCKS, 128, 0, stream>>>(zbuf, h1,
        W1s + (size_t)l * DIM * DIM, b1s + (size_t)l * DIM,
        gammas + (size_t)l * DIM, betas + (size_t)l * DIM,
        W2s + (size_t)l * DIM * DIM, b2s + (size_t)l * DIM);
    hin = h1;
  }

  pool_head_kernel<<<N_GRAPHS, 256, 0, stream>>>(h1, batch, lin1_w, lin1_b, (float*)d_out);
}

// Round 3
// 557.397 us; speedup vs baseline: 1.3611x; 1.1888x over previous
//
#include <hip/hip_runtime.h>

#define N_NODES 100000
#define N_EDGES 1200000
#define DIM 64
#define N_GRAPHS 128
#define N_LAYERS 5

#define NBUCKETS 782          // ceil(100000/128)
#define BCAP 2048             // per-bucket capacity (mean 1534, +13 sigma)
#define CHUNK 8192            // edges per bin block

typedef unsigned short ushort_t;
typedef unsigned int uint_t;

__device__ __forceinline__ float bf2f(uint_t s) {
  return __uint_as_float(s << 16);
}
__device__ __forceinline__ ushort_t f2bf(float f) {
  uint_t u = __float_as_uint(f);
  uint_t r = u + 0x7fffu + ((u >> 16) & 1u);   // RNE
  return (ushort_t)(r >> 16);
}
__device__ __forceinline__ uint_t pack2(float a, float b) {
  return (uint_t)f2bf(a) | ((uint_t)f2bf(b) << 16);
}

// ---------------- fp32 -> bf16 convert (x only, once) ----------------

__global__ __launch_bounds__(256) void conv_kernel(const float* __restrict__ x,
                                                   ushort_t* __restrict__ xb) {
  int i = blockIdx.x * 256 + threadIdx.x;   // 8 elems per thread
  int base = i * 8;
  if (base >= N_NODES * DIM) return;
  float4 a = *(const float4*)(x + base);
  float4 b = *(const float4*)(x + base + 4);
  uint4 o;
  o.x = pack2(a.x, a.y);
  o.y = pack2(a.z, a.w);
  o.z = pack2(b.x, b.y);
  o.w = pack2(b.z, b.w);
  *(uint4*)(xb + base) = o;
}

// ---------------- CSR build: LDS multisplit into 782 buckets ----------------

__global__ __launch_bounds__(256) void bin_kernel(const int* __restrict__ src,
                                                  const int* __restrict__ dst,
                                                  int* __restrict__ gCursor,
                                                  uint_t* __restrict__ gPairs) {
  __shared__ int hist[NBUCKETS];
  __shared__ int lstart[NBUCKETS];
  __shared__ int lcur[NBUCKETS];
  __shared__ int gbase[NBUCKETS];
  __shared__ uint_t pairbuf[CHUNK];
  __shared__ ushort_t bidbuf[CHUNK];
  __shared__ int wsum[4];

  const int t = threadIdx.x;
  const int e0 = blockIdx.x * CHUNK;
  const int ecnt = min(CHUNK, N_EDGES - e0);

  for (int i = t; i < NBUCKETS; i += 256) hist[i] = 0;
  __syncthreads();

  // pass 1: count
  for (int i = t; i < ecnt; i += 256) {
    int d = dst[e0 + i];
    atomicAdd(&hist[d >> 7], 1);
  }
  __syncthreads();

  // exclusive scan of hist[782]: 4 elems/thread + wave shfl scan
  const int base4 = t * 4;
  int h0 = 0, h1 = 0, h2 = 0, h3 = 0;
  if (base4 + 0 < NBUCKETS) h0 = hist[base4 + 0];
  if (base4 + 1 < NBUCKETS) h1 = hist[base4 + 1];
  if (base4 + 2 < NBUCKETS) h2 = hist[base4 + 2];
  if (base4 + 3 < NBUCKETS) h3 = hist[base4 + 3];
  int tsum = h0 + h1 + h2 + h3;
  int lane = t & 63, wid = t >> 6;
  int inc = tsum;
  #pragma unroll
  for (int off = 1; off < 64; off <<= 1) {
    int v = __shfl_up(inc, off);
    if (lane >= off) inc += v;
  }
  if (lane == 63) wsum[wid] = inc;
  __syncthreads();
  int wadd = 0;
  for (int w = 0; w < wid; ++w) wadd += wsum[w];
  int ex = wadd + inc - tsum;
  if (base4 + 0 < NBUCKETS) { lstart[base4 + 0] = ex; lcur[base4 + 0] = ex; } ex += h0;
  if (base4 + 1 < NBUCKETS) { lstart[base4 + 1] = ex; lcur[base4 + 1] = ex; } ex += h1;
  if (base4 + 2 < NBUCKETS) { lstart[base4 + 2] = ex; lcur[base4 + 2] = ex; } ex += h2;
  if (base4 + 3 < NBUCKETS) { lstart[base4 + 3] = ex; lcur[base4 + 3] = ex; }
  __syncthreads();

  // pass 2: local scatter (bucket-sorted within block)
  for (int i = t; i < ecnt; i += 256) {
    int s = src[e0 + i];
    int d = dst[e0 + i];
    int b = d >> 7;
    int p = atomicAdd(&lcur[b], 1);
    pairbuf[p] = (uint_t)s | ((uint_t)(d & 127) << 17);
    bidbuf[p] = (ushort_t)b;
  }
  __syncthreads();

  // reserve global space per bucket
  for (int b = t; b < NBUCKETS; b += 256) {
    int cnt = lcur[b] - lstart[b];
    gbase[b] = cnt ? atomicAdd(&gCursor[b], cnt) : 0;
  }
  __syncthreads();

  // flush runs (coalesced)
  for (int i = t; i < ecnt; i += 256) {
    int b = bidbuf[i];
    int pos = gbase[b] + (i - lstart[b]);
    if (pos < BCAP) gPairs[b * BCAP + pos] = pairbuf[i];
  }
}

__global__ __launch_bounds__(1024) void bscan_kernel(const int* __restrict__ gCursor,
                                                     int* __restrict__ bucketBase) {
  __shared__ int sm[1024];
  int t = threadIdx.x;
  int v = (t < NBUCKETS) ? min(gCursor[t], BCAP) : 0;
  sm[t] = v;
  __syncthreads();
  for (int off = 1; off < 1024; off <<= 1) {
    int x = (t >= off) ? sm[t - off] : 0;
    __syncthreads();
    sm[t] += x;
    __syncthreads();
  }
  bucketBase[t] = sm[t] - v;                       // exclusive
  if (t == NBUCKETS - 1) bucketBase[NBUCKETS] = sm[t];
}

// per-bucket counting sort -> rowptr + ssrc
__global__ __launch_bounds__(256) void csort_kernel(const int* __restrict__ gCursor,
                                                    const int* __restrict__ bucketBase,
                                                    const uint_t* __restrict__ gPairs,
                                                    int* __restrict__ rowptr,
                                                    int* __restrict__ ssrc) {
  __shared__ uint_t vals[BCAP];
  __shared__ int ssl[BCAP];
  __shared__ int nh[128];
  __shared__ int ncur[128];
  __shared__ int w0sum;

  const int b = blockIdx.x, t = threadIdx.x;
  const int cnt = min(gCursor[b], BCAP);
  const int base = bucketBase[b];
  const int n0 = b << 7;
  const int nn = min(128, N_NODES - n0);

  if (t < 128) nh[t] = 0;
  __syncthreads();
  for (int i = t; i < cnt; i += 256) {
    uint_t v = gPairs[b * BCAP + i];
    vals[i] = v;
    atomicAdd(&nh[(v >> 17) & 127], 1);
  }
  __syncthreads();

  int inc = 0, v = 0;
  if (t < 128) {
    v = nh[t];
    inc = v;
    int lane = t & 63;
    #pragma unroll
    for (int off = 1; off < 64; off <<= 1) {
      int x = __shfl_up(inc, off);
      if (lane >= off) inc += x;
    }
    if (t == 63) w0sum = inc;
  }
  __syncthreads();
  if (t < 128) {
    int e = inc - v + ((t >= 64) ? w0sum : 0);   // exclusive prefix
    ncur[t] = e;
    if (t < nn) rowptr[n0 + t] = base + e;
  }
  if (b == NBUCKETS - 1 && t == 0) rowptr[N_NODES] = base + cnt;
  __syncthreads();

  for (int i = t; i < cnt; i += 256) {
    uint_t vv = vals[i];
    int j = (vv >> 17) & 127;
    int p = atomicAdd(&ncur[j], 1);
    ssl[p] = (int)(vv & 0x1FFFF);
  }
  __syncthreads();
  for (int i = t; i < cnt; i += 256) ssrc[base + i] = ssl[i];
}

// ---------------- aggregation: z = h + sum_{j in N(i)} h_j ----------------
// 4 edges per wave-load: lane l -> edge slot l>>4, dims ((l&15)*4) as uint2.

__global__ __launch_bounds__(256) void agg_kernel(const ushort_t* __restrict__ h,
                                                  const int* __restrict__ rowptr,
                                                  const int* __restrict__ ssrc,
                                                  float* __restrict__ z) {
  int node = blockIdx.x * 4 + (threadIdx.x >> 6);
  int l = threadIdx.x & 63;
  if (node >= N_NODES) return;
  int sub = l >> 4;
  int dp = (l & 15) << 2;
  float a0 = 0.f, a1 = 0.f, a2 = 0.f, a3 = 0.f;
  if (sub == 0) {
    uint2 r = *(const uint2*)(h + node * DIM + dp);
    a0 = bf2f(r.x & 0xffffu); a1 = bf2f(r.x >> 16);
    a2 = bf2f(r.y & 0xffffu); a3 = bf2f(r.y >> 16);
  }
  int s = rowptr[node], e = rowptr[node + 1];
  #pragma unroll 2
  for (int j = s; j < e; j += 4) {
    int idx = j + sub;
    if (idx < e) {
      int u = ssrc[idx];
      uint2 r = *(const uint2*)(h + u * DIM + dp);
      a0 += bf2f(r.x & 0xffffu); a1 += bf2f(r.x >> 16);
      a2 += bf2f(r.y & 0xffffu); a3 += bf2f(r.y >> 16);
    }
  }
  a0 += __shfl_xor(a0, 16); a1 += __shfl_xor(a1, 16);
  a2 += __shfl_xor(a2, 16); a3 += __shfl_xor(a3, 16);
  a0 += __shfl_xor(a0, 32); a1 += __shfl_xor(a1, 32);
  a2 += __shfl_xor(a2, 32); a3 += __shfl_xor(a3, 32);
  if (sub == 0) {
    *(float4*)(z + node * DIM + dp) = make_float4(a0, a1, a2, a3);
  }
}

// ---------------- fused MLP: out = relu((relu((z@W1+b1)*s+t))@W2+b2) ----------------

#define ZSTRIDE 68

__global__ __launch_bounds__(128) void mlp_kernel(const float* __restrict__ z,
                                                  ushort_t* __restrict__ hout,
                                                  const float* __restrict__ W1,
                                                  const float* __restrict__ b1,
                                                  const float* __restrict__ gam,
                                                  const float* __restrict__ bet,
                                                  const float* __restrict__ W2,
                                                  const float* __restrict__ b2) {
  __shared__ float zs[128 * ZSTRIDE];
  __shared__ float wls[64 * 64];
  const int t = threadIdx.x;
  const int base = blockIdx.x * 128;

  #pragma unroll
  for (int i = 0; i < 16; ++i) {
    int f = i * 128 + t;
    int n = f >> 4;
    int d = (f & 15) << 2;
    int gn = base + n;
    if (gn >= N_NODES) gn = N_NODES - 1;
    *(float4*)(zs + n * ZSTRIDE + d) = *(const float4*)(z + gn * DIM + d);
  }
  #pragma unroll
  for (int i = 0; i < 8; ++i) {
    int f = (i * 128 + t) * 4;
    *(float4*)(wls + f) = *(const float4*)(W1 + f);
  }
  __syncthreads();

  const int m = t & 7;
  const int gq = t >> 3;
  const int c0 = m * 8;

  float acc[8][8];
  #pragma unroll
  for (int j = 0; j < 8; ++j)
    #pragma unroll
    for (int i = 0; i < 8; ++i) acc[j][i] = 0.f;

  #pragma unroll 2
  for (int k0 = 0; k0 < 64; k0 += 4) {
    float zv[8][4];
    #pragma unroll
    for (int j = 0; j < 8; ++j)
      *(float4*)zv[j] = *(const float4*)(zs + (gq + 16 * j) * ZSTRIDE + k0);
    #pragma unroll
    for (int kk = 0; kk < 4; ++kk) {
      float wa[8];
      *(float4*)&wa[0] = *(const float4*)(wls + (k0 + kk) * 64 + c0);
      *(float4*)&wa[4] = *(const float4*)(wls + (k0 + kk) * 64 + c0 + 4);
      #pragma unroll
      for (int j = 0; j < 8; ++j) {
        float zz = zv[j][kk];
        #pragma unroll
        for (int i = 0; i < 8; ++i) acc[j][i] = fmaf(zz, wa[i], acc[j][i]);
      }
    }
  }

  const float BNR = 0.99999500003749971893f;   // 1/sqrt(1+1e-5)
  float s_[8], o_[8];
  #pragma unroll
  for (int i = 0; i < 8; ++i) {
    float sc = gam[c0 + i] * BNR;
    s_[i] = sc;
    o_[i] = fmaf(b1[c0 + i], sc, bet[c0 + i]);
  }
  #pragma unroll
  for (int j = 0; j < 8; ++j)
    #pragma unroll
    for (int i = 0; i < 8; ++i) {
      float v = fmaf(acc[j][i], s_[i], o_[i]);
      acc[j][i] = v > 0.f ? v : 0.f;
    }

  __syncthreads();

  #pragma unroll
  for (int j = 0; j < 8; ++j) {
    int n = gq + 16 * j;
    *(float4*)(zs + n * ZSTRIDE + c0) = make_float4(acc[j][0], acc[j][1], acc[j][2], acc[j][3]);
    *(float4*)(zs + n * ZSTRIDE + c0 + 4) = make_float4(acc[j][4], acc[j][5], acc[j][6], acc[j][7]);
  }
  #pragma unroll
  for (int i = 0; i < 8; ++i) {
    int f = (i * 128 + t) * 4;
    *(float4*)(wls + f) = *(const float4*)(W2 + f);
  }
  __syncthreads();

  float acc2[8][8];
  #pragma unroll
  for (int j = 0; j < 8; ++j)
    #pragma unroll
    for (int i = 0; i < 8; ++i) acc2[j][i] = 0.f;

  #pragma unroll 2
  for (int k0 = 0; k0 < 64; k0 += 4) {
    float zv[8][4];
    #pragma unroll
    for (int j = 0; j < 8; ++j)
      *(float4*)zv[j] = *(const float4*)(zs + (gq + 16 * j) * ZSTRIDE + k0);
    #pragma unroll
    for (int kk = 0; kk < 4; ++kk) {
      float wa[8];
      *(float4*)&wa[0] = *(const float4*)(wls + (k0 + kk) * 64 + c0);
      *(float4*)&wa[4] = *(const float4*)(wls + (k0 + kk) * 64 + c0 + 4);
      #pragma unroll
      for (int j = 0; j < 8; ++j) {
        float zz = zv[j][kk];
        #pragma unroll
        for (int i = 0; i < 8; ++i) acc2[j][i] = fmaf(zz, wa[i], acc2[j][i]);
      }
    }
  }

  float bb[8];
  #pragma unroll
  for (int i = 0; i < 8; ++i) bb[i] = b2[c0 + i];
  #pragma unroll
  for (int j = 0; j < 8; ++j) {
    int gn = base + gq + 16 * j;
    if (gn < N_NODES) {
      uint4 o;
      float v0 = fmaxf(acc2[j][0] + bb[0], 0.f);
      float v1 = fmaxf(acc2[j][1] + bb[1], 0.f);
      float v2 = fmaxf(acc2[j][2] + bb[2], 0.f);
      float v3 = fmaxf(acc2[j][3] + bb[3], 0.f);
      float v4 = fmaxf(acc2[j][4] + bb[4], 0.f);
      float v5 = fmaxf(acc2[j][5] + bb[5], 0.f);
      float v6 = fmaxf(acc2[j][6] + bb[6], 0.f);
      float v7 = fmaxf(acc2[j][7] + bb[7], 0.f);
      o.x = pack2(v0, v1);
      o.y = pack2(v2, v3);
      o.z = pack2(v4, v5);
      o.w = pack2(v6, v7);
      *(uint4*)(hout + gn * DIM + c0) = o;
    }
  }
}

// ---------------- pool (batch is sorted) + head ----------------

__global__ __launch_bounds__(256) void pool_head_kernel(const ushort_t* __restrict__ h,
                                                        const int* __restrict__ batch,
                                                        const float* __restrict__ lw,
                                                        const float* __restrict__ lb,
                                                        float* __restrict__ out) {
  __shared__ float red[4][64];
  int g = blockIdx.x;
  int t = threadIdx.x, w = t >> 6, d = t & 63;
  int lo = 0, hi = N_NODES;
  while (lo < hi) { int mid = (lo + hi) >> 1; if (batch[mid] < g) lo = mid + 1; else hi = mid; }
  int start = lo;
  hi = N_NODES;
  while (lo < hi) { int mid = (lo + hi) >> 1; if (batch[mid] < g + 1) lo = mid + 1; else hi = mid; }
  int end = lo;

  float acc = 0.f;
  for (int i = start + w; i < end; i += 4) acc += bf2f((uint_t)h[i * DIM + d]);
  red[w][d] = acc;
  __syncthreads();
  if (w == 0) {
    float prow = red[0][d] + red[1][d] + red[2][d] + red[3][d];
    red[0][d] = prow;
  }
  __syncthreads();
  if (w == 0) {
    float o = lb[d];
    #pragma unroll
    for (int k = 0; k < 64; ++k) o += red[0][k] * lw[k * 64 + d];
    out[g * 64 + d] = fmaxf(o, 0.f);
  }
}

// ---------------- host ----------------

extern "C" void kernel_launch(void* const* d_in, const int* in_sizes, int n_in,
                              void* d_out, int out_size, void* d_ws, size_t ws_size,
                              hipStream_t stream) {
  const float* x      = (const float*)d_in[0];
  const int*   ei     = (const int*)d_in[1];
  const int*   srcp   = ei;
  const int*   dstp   = ei + N_EDGES;
  const int*   batch  = (const int*)d_in[2];
  const float* W1s    = (const float*)d_in[3];
  const float* b1s    = (const float*)d_in[4];
  const float* gammas = (const float*)d_in[5];
  const float* betas  = (const float*)d_in[6];
  const float* W2s    = (const float*)d_in[7];
  const float* b2s    = (const float*)d_in[8];
  const float* lin1_w = (const float*)d_in[9];
  const float* lin1_b = (const float*)d_in[10];

  char* ws = (char*)d_ws;
  const size_t ZBYTES  = (size_t)N_NODES * DIM * sizeof(float);     // 25.6 MB
  const size_t HBBYTES = (size_t)N_NODES * DIM * sizeof(ushort_t);  // 12.8 MB
  float*    zbuf   = (float*)ws;
  uint_t*   gPairs = (uint_t*)ws;                    // aliases zbuf (dead before agg)
  ushort_t* xb     = (ushort_t*)(ws + ZBYTES);
  ushort_t* h1     = (ushort_t*)(ws + ZBYTES + HBBYTES);
  char*     p      = ws + ZBYTES + 2 * HBBYTES;
  int* rowptr     = (int*)p;            p += 100352 * sizeof(int);
  int* ssrc       = (int*)p;            p += (size_t)N_EDGES * sizeof(int);
  int* gCursor    = (int*)p;            p += 1024 * sizeof(int);
  int* bucketBase = (int*)p;

  hipMemsetAsync(gCursor, 0, 1024 * sizeof(int), stream);
  conv_kernel<<<(N_NODES * DIM / 8 + 255) / 256, 256, 0, stream>>>(x, xb);

  const int BIN_BLOCKS = (N_EDGES + CHUNK - 1) / CHUNK;   // 147
  bin_kernel<<<BIN_BLOCKS, 256, 0, stream>>>(srcp, dstp, gCursor, gPairs);
  bscan_kernel<<<1, 1024, 0, stream>>>(gCursor, bucketBase);
  csort_kernel<<<NBUCKETS, 256, 0, stream>>>(gCursor, bucketBase, gPairs, rowptr, ssrc);

  const int AGG_BLOCKS = (N_NODES + 3) / 4;          // 25000
  const int MLP_BLOCKS = (N_NODES + 127) / 128;      // 782

  const ushort_t* hin = xb;
  for (int l = 0; l < N_LAYERS; ++l) {
    agg_kernel<<<AGG_BLOCKS, 256, 0, stream>>>(hin, rowptr, ssrc, zbuf);
    mlp_kernel<<<MLP_BLOCKS, 128, 0, stream>>>(zbuf, h1,
        W1s + (size_t)l * DIM * DIM, b1s + (size_t)l * DIM,
        gammas + (size_t)l * DIM, betas + (size_t)l * DIM,
        W2s + (size_t)l * DIM * DIM, b2s + (size_t)l * DIM);
    hin = h1;
  }

  pool_head_kernel<<<N_GRAPHS, 256, 0, stream>>>(h1, batch, lin1_w, lin1_b, (float*)d_out);
}

// Round 4
// 475.813 us; speedup vs baseline: 1.5945x; 1.1715x over previous
//
#include <hip/hip_runtime.h>

#define N_NODES 100000
#define N_EDGES 1200000
#define DIM 64
#define N_GRAPHS 128
#define N_LAYERS 5

#define NBUCKETS 782          // ceil(100000/128)
#define BCAP 2048             // per-bucket capacity (mean 1534, +13 sigma)
#define CHUNK 8192            // edges per bin block

#define POOL_CH 196           // nodes per pool block -> 511 blocks
#define POOL_BLOCKS ((N_NODES + POOL_CH - 1) / POOL_CH)

typedef unsigned short ushort_t;
typedef unsigned int uint_t;

__device__ __forceinline__ float bf2f(uint_t s) {
  return __uint_as_float(s << 16);
}
__device__ __forceinline__ ushort_t f2bf(float f) {
  uint_t u = __float_as_uint(f);
  uint_t r = u + 0x7fffu + ((u >> 16) & 1u);   // RNE
  return (ushort_t)(r >> 16);
}
__device__ __forceinline__ uint_t pack2(float a, float b) {
  return (uint_t)f2bf(a) | ((uint_t)f2bf(b) << 16);
}

// ---------------- fp32 -> bf16 convert (x only, once) ----------------

__global__ __launch_bounds__(256) void conv_kernel(const float* __restrict__ x,
                                                   ushort_t* __restrict__ xb) {
  int i = blockIdx.x * 256 + threadIdx.x;   // 8 elems per thread
  int base = i * 8;
  if (base >= N_NODES * DIM) return;
  float4 a = *(const float4*)(x + base);
  float4 b = *(const float4*)(x + base + 4);
  uint4 o;
  o.x = pack2(a.x, a.y);
  o.y = pack2(a.z, a.w);
  o.z = pack2(b.x, b.y);
  o.w = pack2(b.z, b.w);
  *(uint4*)(xb + base) = o;
}

// ---------------- CSR build: LDS multisplit into 782 buckets ----------------

__global__ __launch_bounds__(256) void bin_kernel(const int* __restrict__ src,
                                                  const int* __restrict__ dst,
                                                  int* __restrict__ gCursor,
                                                  uint_t* __restrict__ gPairs) {
  __shared__ int hist[NBUCKETS];
  __shared__ int lstart[NBUCKETS];
  __shared__ int lcur[NBUCKETS];
  __shared__ int gbase[NBUCKETS];
  __shared__ uint_t pairbuf[CHUNK];
  __shared__ ushort_t bidbuf[CHUNK];
  __shared__ int wsum[4];

  const int t = threadIdx.x;
  const int e0 = blockIdx.x * CHUNK;
  const int ecnt = min(CHUNK, N_EDGES - e0);

  for (int i = t; i < NBUCKETS; i += 256) hist[i] = 0;
  __syncthreads();

  // pass 1: count
  for (int i = t; i < ecnt; i += 256) {
    int d = dst[e0 + i];
    atomicAdd(&hist[d >> 7], 1);
  }
  __syncthreads();

  // exclusive scan of hist[782]: 4 elems/thread + wave shfl scan
  const int base4 = t * 4;
  int h0 = 0, h1 = 0, h2 = 0, h3 = 0;
  if (base4 + 0 < NBUCKETS) h0 = hist[base4 + 0];
  if (base4 + 1 < NBUCKETS) h1 = hist[base4 + 1];
  if (base4 + 2 < NBUCKETS) h2 = hist[base4 + 2];
  if (base4 + 3 < NBUCKETS) h3 = hist[base4 + 3];
  int tsum = h0 + h1 + h2 + h3;
  int lane = t & 63, wid = t >> 6;
  int inc = tsum;
  #pragma unroll
  for (int off = 1; off < 64; off <<= 1) {
    int v = __shfl_up(inc, off);
    if (lane >= off) inc += v;
  }
  if (lane == 63) wsum[wid] = inc;
  __syncthreads();
  int wadd = 0;
  for (int w = 0; w < wid; ++w) wadd += wsum[w];
  int ex = wadd + inc - tsum;
  if (base4 + 0 < NBUCKETS) { lstart[base4 + 0] = ex; lcur[base4 + 0] = ex; } ex += h0;
  if (base4 + 1 < NBUCKETS) { lstart[base4 + 1] = ex; lcur[base4 + 1] = ex; } ex += h1;
  if (base4 + 2 < NBUCKETS) { lstart[base4 + 2] = ex; lcur[base4 + 2] = ex; } ex += h2;
  if (base4 + 3 < NBUCKETS) { lstart[base4 + 3] = ex; lcur[base4 + 3] = ex; }
  __syncthreads();

  // pass 2: local scatter (bucket-sorted within block)
  for (int i = t; i < ecnt; i += 256) {
    int s = src[e0 + i];
    int d = dst[e0 + i];
    int b = d >> 7;
    int p = atomicAdd(&lcur[b], 1);
    pairbuf[p] = (uint_t)s | ((uint_t)(d & 127) << 17);
    bidbuf[p] = (ushort_t)b;
  }
  __syncthreads();

  // reserve global space per bucket
  for (int b = t; b < NBUCKETS; b += 256) {
    int cnt = lcur[b] - lstart[b];
    gbase[b] = cnt ? atomicAdd(&gCursor[b], cnt) : 0;
  }
  __syncthreads();

  // flush runs (coalesced)
  for (int i = t; i < ecnt; i += 256) {
    int b = bidbuf[i];
    int pos = gbase[b] + (i - lstart[b]);
    if (pos < BCAP) gPairs[b * BCAP + pos] = pairbuf[i];
  }
}

__global__ __launch_bounds__(1024) void bscan_kernel(const int* __restrict__ gCursor,
                                                     int* __restrict__ bucketBase) {
  __shared__ int sm[1024];
  int t = threadIdx.x;
  int v = (t < NBUCKETS) ? min(gCursor[t], BCAP) : 0;
  sm[t] = v;
  __syncthreads();
  for (int off = 1; off < 1024; off <<= 1) {
    int x = (t >= off) ? sm[t - off] : 0;
    __syncthreads();
    sm[t] += x;
    __syncthreads();
  }
  bucketBase[t] = sm[t] - v;                       // exclusive
  if (t == NBUCKETS - 1) bucketBase[NBUCKETS] = sm[t];
}

// per-bucket counting sort -> rowptr + ssrc
__global__ __launch_bounds__(256) void csort_kernel(const int* __restrict__ gCursor,
                                                    const int* __restrict__ bucketBase,
                                                    const uint_t* __restrict__ gPairs,
                                                    int* __restrict__ rowptr,
                                                    int* __restrict__ ssrc) {
  __shared__ uint_t vals[BCAP];
  __shared__ int ssl[BCAP];
  __shared__ int nh[128];
  __shared__ int ncur[128];
  __shared__ int w0sum;

  const int b = blockIdx.x, t = threadIdx.x;
  const int cnt = min(gCursor[b], BCAP);
  const int base = bucketBase[b];
  const int n0 = b << 7;
  const int nn = min(128, N_NODES - n0);

  if (t < 128) nh[t] = 0;
  __syncthreads();
  for (int i = t; i < cnt; i += 256) {
    uint_t v = gPairs[b * BCAP + i];
    vals[i] = v;
    atomicAdd(&nh[(v >> 17) & 127], 1);
  }
  __syncthreads();

  int inc = 0, v = 0;
  if (t < 128) {
    v = nh[t];
    inc = v;
    int lane = t & 63;
    #pragma unroll
    for (int off = 1; off < 64; off <<= 1) {
      int x = __shfl_up(inc, off);
      if (lane >= off) inc += x;
    }
    if (t == 63) w0sum = inc;
  }
  __syncthreads();
  if (t < 128) {
    int e = inc - v + ((t >= 64) ? w0sum : 0);   // exclusive prefix
    ncur[t] = e;
    if (t < nn) rowptr[n0 + t] = base + e;
  }
  if (b == NBUCKETS - 1 && t == 0) rowptr[N_NODES] = base + cnt;
  __syncthreads();

  for (int i = t; i < cnt; i += 256) {
    uint_t vv = vals[i];
    int j = (vv >> 17) & 127;
    int p = atomicAdd(&ncur[j], 1);
    ssl[p] = (int)(vv & 0x1FFFF);
  }
  __syncthreads();
  for (int i = t; i < cnt; i += 256) ssrc[base + i] = ssl[i];
}

// ---------------- aggregation: z = h + sum_{j in N(i)} h_j ----------------
// 8 edges per wave-load: lane l -> edge slot l>>3, dims ((l&7)*8) as uint4 (16B).

__global__ __launch_bounds__(256) void agg_kernel(const ushort_t* __restrict__ h,
                                                  const int* __restrict__ rowptr,
                                                  const int* __restrict__ ssrc,
                                                  float* __restrict__ z) {
  int node = blockIdx.x * 4 + (threadIdx.x >> 6);
  int l = threadIdx.x & 63;
  if (node >= N_NODES) return;
  int sub = l >> 3;           // 0..7 (edge slot within group)
  int dp = (l & 7) << 3;      // dim base: 0,8,..,56
  float a[8];
  #pragma unroll
  for (int i = 0; i < 8; ++i) a[i] = 0.f;
  if (sub == 0) {
    uint4 r = *(const uint4*)(h + node * DIM + dp);
    a[0] = bf2f(r.x & 0xffffu); a[1] = bf2f(r.x >> 16);
    a[2] = bf2f(r.y & 0xffffu); a[3] = bf2f(r.y >> 16);
    a[4] = bf2f(r.z & 0xffffu); a[5] = bf2f(r.z >> 16);
    a[6] = bf2f(r.w & 0xffffu); a[7] = bf2f(r.w >> 16);
  }
  int s = rowptr[node], e = rowptr[node + 1];
  for (int j = s; j < e; j += 8) {
    int idx = j + sub;
    if (idx < e) {
      int u = ssrc[idx];
      uint4 r = *(const uint4*)(h + u * DIM + dp);
      a[0] += bf2f(r.x & 0xffffu); a[1] += bf2f(r.x >> 16);
      a[2] += bf2f(r.y & 0xffffu); a[3] += bf2f(r.y >> 16);
      a[4] += bf2f(r.z & 0xffffu); a[5] += bf2f(r.z >> 16);
      a[6] += bf2f(r.w & 0xffffu); a[7] += bf2f(r.w >> 16);
    }
  }
  #pragma unroll
  for (int i = 0; i < 8; ++i) {
    a[i] += __shfl_xor(a[i], 8);
    a[i] += __shfl_xor(a[i], 16);
    a[i] += __shfl_xor(a[i], 32);
  }
  if (sub == 0) {
    *(float4*)(z + node * DIM + dp)     = make_float4(a[0], a[1], a[2], a[3]);
    *(float4*)(z + node * DIM + dp + 4) = make_float4(a[4], a[5], a[6], a[7]);
  }
}

// ---------------- fused MLP: out = relu((relu((z@W1+b1)*s+t))@W2+b2) ----------------

#define ZSTRIDE 68

__global__ __launch_bounds__(128) void mlp_kernel(const float* __restrict__ z,
                                                  ushort_t* __restrict__ hout,
                                                  const float* __restrict__ W1,
                                                  const float* __restrict__ b1,
                                                  const float* __restrict__ gam,
                                                  const float* __restrict__ bet,
                                                  const float* __restrict__ W2,
                                                  const float* __restrict__ b2) {
  __shared__ float zs[128 * ZSTRIDE];
  __shared__ float wls[64 * 64];
  const int t = threadIdx.x;
  const int base = blockIdx.x * 128;

  #pragma unroll
  for (int i = 0; i < 16; ++i) {
    int f = i * 128 + t;
    int n = f >> 4;
    int d = (f & 15) << 2;
    int gn = base + n;
    if (gn >= N_NODES) gn = N_NODES - 1;
    *(float4*)(zs + n * ZSTRIDE + d) = *(const float4*)(z + gn * DIM + d);
  }
  #pragma unroll
  for (int i = 0; i < 8; ++i) {
    int f = (i * 128 + t) * 4;
    *(float4*)(wls + f) = *(const float4*)(W1 + f);
  }
  __syncthreads();

  const int m = t & 7;
  const int gq = t >> 3;
  const int c0 = m * 8;

  float acc[8][8];
  #pragma unroll
  for (int j = 0; j < 8; ++j)
    #pragma unroll
    for (int i = 0; i < 8; ++i) acc[j][i] = 0.f;

  #pragma unroll 2
  for (int k0 = 0; k0 < 64; k0 += 4) {
    float zv[8][4];
    #pragma unroll
    for (int j = 0; j < 8; ++j)
      *(float4*)zv[j] = *(const float4*)(zs + (gq + 16 * j) * ZSTRIDE + k0);
    #pragma unroll
    for (int kk = 0; kk < 4; ++kk) {
      float wa[8];
      *(float4*)&wa[0] = *(const float4*)(wls + (k0 + kk) * 64 + c0);
      *(float4*)&wa[4] = *(const float4*)(wls + (k0 + kk) * 64 + c0 + 4);
      #pragma unroll
      for (int j = 0; j < 8; ++j) {
        float zz = zv[j][kk];
        #pragma unroll
        for (int i = 0; i < 8; ++i) acc[j][i] = fmaf(zz, wa[i], acc[j][i]);
      }
    }
  }

  const float BNR = 0.99999500003749971893f;   // 1/sqrt(1+1e-5)
  float s_[8], o_[8];
  #pragma unroll
  for (int i = 0; i < 8; ++i) {
    float sc = gam[c0 + i] * BNR;
    s_[i] = sc;
    o_[i] = fmaf(b1[c0 + i], sc, bet[c0 + i]);
  }
  #pragma unroll
  for (int j = 0; j < 8; ++j)
    #pragma unroll
    for (int i = 0; i < 8; ++i) {
      float v = fmaf(acc[j][i], s_[i], o_[i]);
      acc[j][i] = v > 0.f ? v : 0.f;
    }

  __syncthreads();

  #pragma unroll
  for (int j = 0; j < 8; ++j) {
    int n = gq + 16 * j;
    *(float4*)(zs + n * ZSTRIDE + c0) = make_float4(acc[j][0], acc[j][1], acc[j][2], acc[j][3]);
    *(float4*)(zs + n * ZSTRIDE + c0 + 4) = make_float4(acc[j][4], acc[j][5], acc[j][6], acc[j][7]);
  }
  #pragma unroll
  for (int i = 0; i < 8; ++i) {
    int f = (i * 128 + t) * 4;
    *(float4*)(wls + f) = *(const float4*)(W2 + f);
  }
  __syncthreads();

  float acc2[8][8];
  #pragma unroll
  for (int j = 0; j < 8; ++j)
    #pragma unroll
    for (int i = 0; i < 8; ++i) acc2[j][i] = 0.f;

  #pragma unroll 2
  for (int k0 = 0; k0 < 64; k0 += 4) {
    float zv[8][4];
    #pragma unroll
    for (int j = 0; j < 8; ++j)
      *(float4*)zv[j] = *(const float4*)(zs + (gq + 16 * j) * ZSTRIDE + k0);
    #pragma unroll
    for (int kk = 0; kk < 4; ++kk) {
      float wa[8];
      *(float4*)&wa[0] = *(const float4*)(wls + (k0 + kk) * 64 + c0);
      *(float4*)&wa[4] = *(const float4*)(wls + (k0 + kk) * 64 + c0 + 4);
      #pragma unroll
      for (int j = 0; j < 8; ++j) {
        float zz = zv[j][kk];
        #pragma unroll
        for (int i = 0; i < 8; ++i) acc2[j][i] = fmaf(zz, wa[i], acc2[j][i]);
      }
    }
  }

  float bb[8];
  #pragma unroll
  for (int i = 0; i < 8; ++i) bb[i] = b2[c0 + i];
  #pragma unroll
  for (int j = 0; j < 8; ++j) {
    int gn = base + gq + 16 * j;
    if (gn < N_NODES) {
      uint4 o;
      float v0 = fmaxf(acc2[j][0] + bb[0], 0.f);
      float v1 = fmaxf(acc2[j][1] + bb[1], 0.f);
      float v2 = fmaxf(acc2[j][2] + bb[2], 0.f);
      float v3 = fmaxf(acc2[j][3] + bb[3], 0.f);
      float v4 = fmaxf(acc2[j][4] + bb[4], 0.f);
      float v5 = fmaxf(acc2[j][5] + bb[5], 0.f);
      float v6 = fmaxf(acc2[j][6] + bb[6], 0.f);
      float v7 = fmaxf(acc2[j][7] + bb[7], 0.f);
      o.x = pack2(v0, v1);
      o.y = pack2(v2, v3);
      o.z = pack2(v4, v5);
      o.w = pack2(v6, v7);
      *(uint4*)(hout + gn * DIM + c0) = o;
    }
  }
}

// ---------------- pool: partial sums (batch sorted) + tiny head ----------------

__global__ __launch_bounds__(256) void pool_partial_kernel(const ushort_t* __restrict__ h,
                                                           const int* __restrict__ batch,
                                                           float* __restrict__ pooled) {
  int r0 = blockIdx.x * POOL_CH;
  int rend = min(r0 + POOL_CH, N_NODES);
  int w = threadIdx.x >> 6, d = threadIdx.x & 63;
  float acc = 0.f;
  int curg = -1;
  for (int i = r0 + w; i < rend; i += 4) {
    int g = batch[i];                        // wave-uniform
    if (g != curg) {
      if (curg >= 0) atomicAdd(&pooled[curg * DIM + d], acc);
      acc = 0.f;
      curg = g;
    }
    acc += bf2f((uint_t)h[i * DIM + d]);
  }
  if (curg >= 0) atomicAdd(&pooled[curg * DIM + d], acc);
}

__global__ __launch_bounds__(256) void head_kernel(const float* __restrict__ pooled,
                                                   const float* __restrict__ lw,
                                                   const float* __restrict__ lb,
                                                   float* __restrict__ out) {
  int idx = blockIdx.x * 256 + threadIdx.x;
  if (idx >= N_GRAPHS * DIM) return;
  int g = idx >> 6, d = idx & 63;
  float o = lb[d];
  #pragma unroll 8
  for (int k = 0; k < 64; ++k) o = fmaf(pooled[g * 64 + k], lw[k * 64 + d], o);
  out[idx] = fmaxf(o, 0.f);
}

// ---------------- host ----------------

extern "C" void kernel_launch(void* const* d_in, const int* in_sizes, int n_in,
                              void* d_out, int out_size, void* d_ws, size_t ws_size,
                              hipStream_t stream) {
  const float* x      = (const float*)d_in[0];
  const int*   ei     = (const int*)d_in[1];
  const int*   srcp   = ei;
  const int*   dstp   = ei + N_EDGES;
  const int*   batch  = (const int*)d_in[2];
  const float* W1s    = (const float*)d_in[3];
  const float* b1s    = (const float*)d_in[4];
  const float* gammas = (const float*)d_in[5];
  const float* betas  = (const float*)d_in[6];
  const float* W2s    = (const float*)d_in[7];
  const float* b2s    = (const float*)d_in[8];
  const float* lin1_w = (const float*)d_in[9];
  const float* lin1_b = (const float*)d_in[10];

  char* ws = (char*)d_ws;
  const size_t ZBYTES  = (size_t)N_NODES * DIM * sizeof(float);     // 25.6 MB
  const size_t HBBYTES = (size_t)N_NODES * DIM * sizeof(ushort_t);  // 12.8 MB
  float*    zbuf   = (float*)ws;
  uint_t*   gPairs = (uint_t*)ws;                    // aliases zbuf (dead before agg)
  ushort_t* xb     = (ushort_t*)(ws + ZBYTES);
  ushort_t* h1     = (ushort_t*)(ws + ZBYTES + HBBYTES);
  char*     p      = ws + ZBYTES + 2 * HBBYTES;
  int* rowptr     = (int*)p;            p += 100352 * sizeof(int);
  int* ssrc       = (int*)p;            p += (size_t)N_EDGES * sizeof(int);
  int* gCursor    = (int*)p;            p += 1024 * sizeof(int);
  int* bucketBase = (int*)p;            p += 1024 * sizeof(int);
  float* pooled   = (float*)p;

  hipMemsetAsync(gCursor, 0, 1024 * sizeof(int), stream);
  hipMemsetAsync(pooled, 0, N_GRAPHS * DIM * sizeof(float), stream);
  conv_kernel<<<(N_NODES * DIM / 8 + 255) / 256, 256, 0, stream>>>(x, xb);

  const int BIN_BLOCKS = (N_EDGES + CHUNK - 1) / CHUNK;   // 147
  bin_kernel<<<BIN_BLOCKS, 256, 0, stream>>>(srcp, dstp, gCursor, gPairs);
  bscan_kernel<<<1, 1024, 0, stream>>>(gCursor, bucketBase);
  csort_kernel<<<NBUCKETS, 256, 0, stream>>>(gCursor, bucketBase, gPairs, rowptr, ssrc);

  const int AGG_BLOCKS = (N_NODES + 3) / 4;          // 25000
  const int MLP_BLOCKS = (N_NODES + 127) / 128;      // 782

  const ushort_t* hin = xb;
  for (int l = 0; l < N_LAYERS; ++l) {
    agg_kernel<<<AGG_BLOCKS, 256, 0, stream>>>(hin, rowptr, ssrc, zbuf);
    mlp_kernel<<<MLP_BLOCKS, 128, 0, stream>>>(zbuf, h1,
        W1s + (size_t)l * DIM * DIM, b1s + (size_t)l * DIM,
        gammas + (size_t)l * DIM, betas + (size_t)l * DIM,
        W2s + (size_t)l * DIM * DIM, b2s + (size_t)l * DIM);
    hin = h1;
  }

  pool_partial_kernel<<<POOL_BLOCKS, 256, 0, stream>>>(h1, batch, pooled);
  head_kernel<<<(N_GRAPHS * DIM + 255) / 256, 256, 0, stream>>>(pooled, lin1_w, lin1_b, (float*)d_out);
}